// Round 4
// baseline (221.245 us; speedup 1.0000x reference)
//
#include <hip/hip_runtime.h>

// VQ-VAE quantization via bf16-MFMA prefilter + exact fp32 rescore.
// Round 4: latency attack. K-split x2 across blocks (grid 2048 -> ~25 waves/CU),
// per-wave thresholds (no cross-wave exchange), depth-2 register prefetch,
// exact cross-block merge via global u64 atomicMin on (ordbits(dist)<<32|code),
// separate tiny gather kernel.
//   sweep1: per-wave approx max score (mfma 16x16x32 bf16, acc init -0.5||e||^2)
//   sweep2: push candidates >= wave_max - DELTA into block LDS list
//   rescore: exact fp32 distance -> LDS atomicMin -> global atomicMin
// DELTA=0.5 >> 2*eps_bf16(<=0.2 worst case) -> true argmin always captured.

#define NPTS    65536
#define CDIM    64
#define KCODES  4096
#define KSPLIT  2
#define WAVES   4
#define KPB     (KCODES / KSPLIT)   // 2048 codes per block
#define KPW     (KPB / WAVES)       // 512 codes per wave
#define TILES   (KPW / 16)          // 32 tiles of 16 codes
#define LISTCAP 2048
#define DELTA   0.5f

typedef __attribute__((ext_vector_type(8))) short short8;
typedef __attribute__((ext_vector_type(4))) float f32x4;

__device__ __forceinline__ unsigned short f2bf(float x) {
    unsigned u = __float_as_uint(x);
    return (unsigned short)((u + 0x7FFFu + ((u >> 16) & 1u)) >> 16);  // RNE
}

// cb fp32 -> bf16 copy + h[k] = 0.5*||e_k||^2
__global__ __launch_bounds__(256) void vq_prep(const float* __restrict__ cb,
                                               short* __restrict__ cbb,
                                               float* __restrict__ h) {
    int k = blockIdx.x * 256 + threadIdx.x;
    const float4* p = reinterpret_cast<const float4*>(cb + (size_t)k * CDIM);
    float s0 = 0.f, s1 = 0.f, s2 = 0.f, s3 = 0.f;
#pragma unroll
    for (int i = 0; i < 16; i += 2) {
        float4 va = p[i], vb = p[i + 1];
        s0 = fmaf(va.x, va.x, s0); s1 = fmaf(va.y, va.y, s1);
        s2 = fmaf(va.z, va.z, s2); s3 = fmaf(va.w, va.w, s3);
        s0 = fmaf(vb.x, vb.x, s0); s1 = fmaf(vb.y, vb.y, s1);
        s2 = fmaf(vb.z, vb.z, s2); s3 = fmaf(vb.w, vb.w, s3);
        short8 o;
        o[0] = (short)f2bf(va.x); o[1] = (short)f2bf(va.y);
        o[2] = (short)f2bf(va.z); o[3] = (short)f2bf(va.w);
        o[4] = (short)f2bf(vb.x); o[5] = (short)f2bf(vb.y);
        o[6] = (short)f2bf(vb.z); o[7] = (short)f2bf(vb.w);
        *reinterpret_cast<short8*>(cbb + (size_t)k * CDIM + i * 4) = o;
    }
    h[k] = 0.5f * ((s0 + s1) + (s2 + s3));
}

__global__ __launch_bounds__(256) void vq_main(const float* __restrict__ enc,
                                               const float* __restrict__ cbf,
                                               const short* __restrict__ cbb,
                                               const float* __restrict__ h,
                                               unsigned long long* __restrict__ gkey) {
    __shared__ unsigned lcnt;
    __shared__ unsigned list[LISTCAP];
    __shared__ unsigned long long mkey[64];

    const int tid  = threadIdx.x;
    const int wid  = tid >> 6, lane = tid & 63;
    const int lrow = lane & 15, lseg = lane >> 4;
    const int pbase = blockIdx.x * 64;                 // 64 points per block
    const int k0 = blockIdx.y * KPB + wid * KPW;       // this wave's code slice

    if (tid == 0) lcnt = 0;
    if (tid < 64) mkey[tid] = ~0ull;

    // ---- A fragments: the block's 64 points as bf16 ----
    // 16x16x32 A layout: row = lane&15, k = (lane>>4)*8 + e (+32 per kk)
    short8 afr[4][2];
#pragma unroll
    for (int rt = 0; rt < 4; ++rt)
#pragma unroll
        for (int kk = 0; kk < 2; ++kk) {
            const float4* xp = reinterpret_cast<const float4*>(
                enc + (size_t)(pbase + rt * 16 + lrow) * CDIM + kk * 32 + lseg * 8);
            float4 v0 = xp[0], v1 = xp[1];
            short8 a;
            a[0] = (short)f2bf(v0.x); a[1] = (short)f2bf(v0.y);
            a[2] = (short)f2bf(v0.z); a[3] = (short)f2bf(v0.w);
            a[4] = (short)f2bf(v1.x); a[5] = (short)f2bf(v1.y);
            a[6] = (short)f2bf(v1.z); a[7] = (short)f2bf(v1.w);
            afr[rt][kk] = a;
        }
    __syncthreads();   // lcnt/mkey visible before any sweep-2 push

    // B tile loader: 16 codes x 64 dims bf16; per-lane 2x 16B + h dword.
    auto loadB = [&](int ct, short8& x0, short8& x1, float& hh) {
        int code = k0 + ct * 16 + lrow;
        const short* base = cbb + (size_t)code * CDIM + lseg * 8;
        x0 = *reinterpret_cast<const short8*>(base);
        x1 = *reinterpret_cast<const short8*>(base + 32);
        hh = h[code];
    };

    f32x4 best[4];
#pragma unroll
    for (int rt = 0; rt < 4; ++rt)
#pragma unroll
        for (int i = 0; i < 4; ++i) best[rt][i] = -__builtin_inff();

    // ---- sweep 1: per-lane max of (dot - 0.5*esq), depth-2 prefetch ----
    short8 s0b0, s0b1, s1b0, s1b1; float s0h, s1h;
    loadB(0, s0b0, s0b1, s0h);
    loadB(1, s1b0, s1b1, s1h);
    for (int ct = 0; ct < TILES; ct += 2) {
        short8 n0, n1; float nh2;
        loadB(ct + 2 < TILES ? ct + 2 : ct, n0, n1, nh2);
        {
            float nh = -s0h;
            f32x4 acc[4];
#pragma unroll
            for (int rt = 0; rt < 4; ++rt) { acc[rt][0] = nh; acc[rt][1] = nh; acc[rt][2] = nh; acc[rt][3] = nh; }
#pragma unroll
            for (int rt = 0; rt < 4; ++rt)
                acc[rt] = __builtin_amdgcn_mfma_f32_16x16x32_bf16(afr[rt][0], s0b0, acc[rt], 0, 0, 0);
#pragma unroll
            for (int rt = 0; rt < 4; ++rt)
                acc[rt] = __builtin_amdgcn_mfma_f32_16x16x32_bf16(afr[rt][1], s0b1, acc[rt], 0, 0, 0);
#pragma unroll
            for (int rt = 0; rt < 4; ++rt)
#pragma unroll
                for (int i = 0; i < 4; ++i) best[rt][i] = fmaxf(best[rt][i], acc[rt][i]);
        }
        s0b0 = n0; s0b1 = n1; s0h = nh2;
        loadB(ct + 3 < TILES ? ct + 3 : ct, n0, n1, nh2);
        {
            float nh = -s1h;
            f32x4 acc[4];
#pragma unroll
            for (int rt = 0; rt < 4; ++rt) { acc[rt][0] = nh; acc[rt][1] = nh; acc[rt][2] = nh; acc[rt][3] = nh; }
#pragma unroll
            for (int rt = 0; rt < 4; ++rt)
                acc[rt] = __builtin_amdgcn_mfma_f32_16x16x32_bf16(afr[rt][0], s1b0, acc[rt], 0, 0, 0);
#pragma unroll
            for (int rt = 0; rt < 4; ++rt)
                acc[rt] = __builtin_amdgcn_mfma_f32_16x16x32_bf16(afr[rt][1], s1b1, acc[rt], 0, 0, 0);
#pragma unroll
            for (int rt = 0; rt < 4; ++rt)
#pragma unroll
                for (int i = 0; i < 4; ++i) best[rt][i] = fmaxf(best[rt][i], acc[rt][i]);
        }
        s1b0 = n0; s1b1 = n1; s1h = nh2;
    }

    // intra-wave max over the 16 col-lanes (codes dim), then threshold
#pragma unroll
    for (int m = 1; m <= 8; m <<= 1)
#pragma unroll
        for (int rt = 0; rt < 4; ++rt)
#pragma unroll
            for (int i = 0; i < 4; ++i)
                best[rt][i] = fmaxf(best[rt][i], __shfl_xor(best[rt][i], m, 64));
#pragma unroll
    for (int rt = 0; rt < 4; ++rt)
#pragma unroll
        for (int i = 0; i < 4; ++i) best[rt][i] -= DELTA;   // per-wave threshold

    // ---- sweep 2: identical acc; push candidates >= threshold ----
    loadB(0, s0b0, s0b1, s0h);
    loadB(1, s1b0, s1b1, s1h);
    for (int ct = 0; ct < TILES; ct += 2) {
        short8 n0, n1; float nh2;
        loadB(ct + 2 < TILES ? ct + 2 : ct, n0, n1, nh2);
        {
            float nh = -s0h;
            f32x4 acc[4];
#pragma unroll
            for (int rt = 0; rt < 4; ++rt) { acc[rt][0] = nh; acc[rt][1] = nh; acc[rt][2] = nh; acc[rt][3] = nh; }
#pragma unroll
            for (int rt = 0; rt < 4; ++rt)
                acc[rt] = __builtin_amdgcn_mfma_f32_16x16x32_bf16(afr[rt][0], s0b0, acc[rt], 0, 0, 0);
#pragma unroll
            for (int rt = 0; rt < 4; ++rt)
                acc[rt] = __builtin_amdgcn_mfma_f32_16x16x32_bf16(afr[rt][1], s0b1, acc[rt], 0, 0, 0);
#pragma unroll
            for (int rt = 0; rt < 4; ++rt)
#pragma unroll
                for (int i = 0; i < 4; ++i)
                    if (acc[rt][i] >= best[rt][i]) {
                        int row = rt * 16 + lseg * 4 + i;           // C/D row map (m89)
                        unsigned e = ((unsigned)row << 12) | (unsigned)(k0 + ct * 16 + lrow);
                        unsigned pos = atomicAdd(&lcnt, 1u);
                        if (pos < LISTCAP) list[pos] = e;
                    }
        }
        s0b0 = n0; s0b1 = n1; s0h = nh2;
        loadB(ct + 3 < TILES ? ct + 3 : ct, n0, n1, nh2);
        {
            float nh = -s1h;
            f32x4 acc[4];
#pragma unroll
            for (int rt = 0; rt < 4; ++rt) { acc[rt][0] = nh; acc[rt][1] = nh; acc[rt][2] = nh; acc[rt][3] = nh; }
#pragma unroll
            for (int rt = 0; rt < 4; ++rt)
                acc[rt] = __builtin_amdgcn_mfma_f32_16x16x32_bf16(afr[rt][0], s1b0, acc[rt], 0, 0, 0);
#pragma unroll
            for (int rt = 0; rt < 4; ++rt)
                acc[rt] = __builtin_amdgcn_mfma_f32_16x16x32_bf16(afr[rt][1], s1b1, acc[rt], 0, 0, 0);
#pragma unroll
            for (int rt = 0; rt < 4; ++rt)
#pragma unroll
                for (int i = 0; i < 4; ++i)
                    if (acc[rt][i] >= best[rt][i]) {
                        int row = rt * 16 + lseg * 4 + i;
                        unsigned e = ((unsigned)row << 12) | (unsigned)(k0 + (ct + 1) * 16 + lrow);
                        unsigned pos = atomicAdd(&lcnt, 1u);
                        if (pos < LISTCAP) list[pos] = e;
                    }
        }
        s1b0 = n0; s1b1 = n1; s1h = nh2;
    }
    __syncthreads();

    // ---- exact fp32 rescore of candidates (block-wide) ----
    unsigned cnt = lcnt; if (cnt > LISTCAP) cnt = LISTCAP;
    for (unsigned t = tid; t < cnt; t += 256) {
        unsigned e = list[t];
        int row = (int)(e >> 12), c = (int)(e & 4095u);
        const float4* xp = reinterpret_cast<const float4*>(enc + (size_t)(pbase + row) * CDIM);
        const float4* ep = reinterpret_cast<const float4*>(cbf + (size_t)c * CDIM);
        float a0 = 0.f, a1 = 0.f, a2 = 0.f, a3 = 0.f;
#pragma unroll
        for (int i = 0; i < 16; ++i) {
            float4 xv = xp[i], ev = ep[i];
            a0 = fmaf(xv.x, ev.x, a0); a1 = fmaf(xv.y, ev.y, a1);
            a2 = fmaf(xv.z, ev.z, a2); a3 = fmaf(xv.w, ev.w, a3);
        }
        float dot = (a0 + a1) + (a2 + a3);
        float d2 = fmaf(-2.f, dot, 2.f * h[c]);               // esq - 2*dot (bit-identical across blocks)
        unsigned bb = __float_as_uint(d2);
        unsigned ord = bb ^ (unsigned)(((int)bb >> 31) | 0x80000000);  // monotonic
        atomicMin(&mkey[row], ((unsigned long long)ord << 32) | (unsigned)c);
    }
    __syncthreads();

    // ---- exact cross-block merge ----
    if (tid < 64) atomicMin(&gkey[pbase + tid], mkey[tid]);
}

__global__ __launch_bounds__(256) void vq_fin(const float* __restrict__ cbf,
                                              const unsigned long long* __restrict__ gkey,
                                              float* __restrict__ out) {
    const int tid = threadIdx.x;
    const int n = blockIdx.x * 64 + (tid >> 2);
    const int q = tid & 3;
    const int c = (int)(gkey[n] & 4095u);
    const float4* ep = reinterpret_cast<const float4*>(cbf + (size_t)c * CDIM) + q * 4;
    float4* op = reinterpret_cast<float4*>(out + (size_t)n * CDIM) + q * 4;
#pragma unroll
    for (int i = 0; i < 4; ++i) op[i] = ep[i];
    if (q == 0) out[(size_t)NPTS * CDIM + n] = (float)c;
}

extern "C" void kernel_launch(void* const* d_in, const int* in_sizes, int n_in,
                              void* d_out, int out_size, void* d_ws, size_t ws_size,
                              hipStream_t stream) {
    const float* enc = (const float*)d_in[0];
    const float* cb  = (const float*)d_in[1];
    float* out = (float*)d_out;

    // ws: cbb bf16[4096*64] (512KB) | h fp32[4096] (16KB) | gkey u64[65536] (512KB)
    short* cbb = (short*)d_ws;
    float* hws = (float*)(cbb + (size_t)KCODES * CDIM);
    unsigned long long* gkey = (unsigned long long*)(hws + KCODES);

    vq_prep<<<KCODES / 256, 256, 0, stream>>>(cb, cbb, hws);
    hipMemsetAsync(gkey, 0xFF, (size_t)NPTS * sizeof(unsigned long long), stream);
    dim3 grid(NPTS / 64, KSPLIT);
    vq_main<<<grid, 256, 0, stream>>>(enc, cb, cbb, hws, gkey);
    vq_fin<<<NPTS / 64, 256, 0, stream>>>(cb, gkey, out);
}